// Round 2
// 436.782 us; speedup vs baseline: 1.1674x; 1.1674x over previous
//
#include <hip/hip_runtime.h>

// Problem constants
#define B_  4096
#define D_  1024
#define R_  2048
#define MAXD 2560

typedef _Float16 half8 __attribute__((ext_vector_type(8)));  // 8 fp16 = 4 VGPRs (MFMA frag)
typedef _Float16 half4 __attribute__((ext_vector_type(4)));  // 8-byte LDS store
typedef float    f32x4 __attribute__((ext_vector_type(4)));

constexpr int BM = 128;      // M tile (batch rows)
constexpr int BN = 64;       // N tile (reservoir cols)
constexpr int BK = 32;       // K chunk (elems)
constexpr int NCHUNK = (D_ + R_) / BK;   // 96
constexpr int NCH1   = D_ / BK;          // 32 (gate + Win phase)

// PRECISE activations (round-0-verified). Do NOT substitute fast approximations:
// the spike-subtract at 0.5 is a discontinuity -- any epsilon of extra numeric
// error flips elements across it for a 0.5-sized absmax (round-1 post-mortem).
__device__ __forceinline__ float sigmoidf_(float x) { return 1.0f / (1.0f + expf(-x)); }

// Raw workgroup barrier: waits LDS ops only (lgkmcnt), NOT vmcnt -> the register
// prefetch loads stay in flight across the barrier (T4-lite). sched_barrier(0)
// fences both sides so ds ops / reg-only MFMAs can't migrate across (rule #18).
__device__ __forceinline__ void wg_barrier() {
    __builtin_amdgcn_sched_barrier(0);
    asm volatile("s_waitcnt lgkmcnt(0)" ::: "memory");
    __builtin_amdgcn_s_barrier();
    __builtin_amdgcn_sched_barrier(0);
}

// Fused: pre = X*Win^T + prev*Wres^T (K=3072), gates = X*Wgate^T (K=1024, 3 sets),
// state = o*( 0.9*f*prev + 0.1*tanh(i*pre) ), spike-subtract, fp32 store.
//
// Numerics: 3-term fp16 split (hh + lh + hl, lo*lo dropped) -- state error ~1e-7,
// verified zero threshold-flips in round 0 (absmax = 1 bf16 ulp). The 2-term
// variant (~1e-4) flipped hundreds of elements across the 0.5 spike threshold.
//
// LDS is FRAGMENT-MAJOR with XOR swizzle: element (r,k) of a 16-row group lives
// at half-index ((r&15)^q)*8 + q*128 + (k&7), q = k>>3.
//  - frag read: lane l reads 8 contiguous halves at ((fr^q)*8 + q*128),
//    fr=l&15, q=l>>4 -> 64 distinct 16B chunks covering 1024B: conflict-free.
//  - staging write: the ^q spreads each 8-lane row-group over 16 banks ->
//    half4 writes hit the 4-cycle wave minimum (was 4-way conflicted unswizzled).
__global__ __launch_bounds__(256, 2)
void reservoir_fused(const float* __restrict__ X,     // B x D
                     const float* __restrict__ P,     // B x MAXD (use first R cols)
                     const float* __restrict__ Win,   // R x D
                     const float* __restrict__ Wres,  // R x R
                     const float* __restrict__ Wg,    // 3R x D
                     float* __restrict__ out)         // B x MAXD
{
    __shared__ _Float16 sA[2][8][512];      // [hi/lo][rowgroup16][frag halves] 16 KB
    __shared__ _Float16 sW[2][4][4][512];   // [hi/lo][set][colgroup][...]      32 KB

    const int tid  = threadIdx.x;
    const int lane = tid & 63;
    const int wv   = tid >> 6;                      // wave id 0..3
    const int m0   = blockIdx.y * BM;
    const int n0   = blockIdx.x * BN;

    f32x4 acc[4][2][4];                              // [set][mtile][ntile]
    #pragma unroll
    for (int s = 0; s < 4; ++s)
        #pragma unroll
        for (int mt = 0; mt < 2; ++mt)
            #pragma unroll
            for (int nt = 0; nt < 4; ++nt) acc[s][mt][nt] = (f32x4){0.f, 0.f, 0.f, 0.f};

    // staging coordinates: thread covers (row = crow + 32i, k = c4..c4+3)
    const int crow = tid >> 3;            // 0..31
    const int c4   = (tid & 7) * 4;       // 0,4,...,28
    const int q    = c4 >> 3;             // k-octet 0..3
    // swizzled half-offset for this thread's k-chunk, given row r:
    //   idx(r) = ((r&15)^q)*8 + q*128 + (c4&4)
    const int fbase = q * 128 + (c4 & 4);

    // frag read offset for this lane (halves)
    const int raddr = ((((lane & 15) ^ (lane >> 4)) << 3) + ((lane >> 4) << 7));

    // register prefetch buffers (next chunk's raw fp32)
    f32x4 pa[4];                          // A tile: 128 rows
    f32x4 pw[8];                          // [0..1]=pre W, [2..7]=gate W (phase1 only)

    auto issue_loads = [&](int t) {
        if (t < NCH1) {
            const int kc = t * BK + c4;
            const float* a = X + (size_t)m0 * D_ + kc;
            #pragma unroll
            for (int i = 0; i < 4; ++i)
                pa[i] = *(const f32x4*)(a + (size_t)(crow + 32 * i) * D_);
            const float* w = Win + (size_t)n0 * D_ + kc;
            #pragma unroll
            for (int i = 0; i < 2; ++i)
                pw[i] = *(const f32x4*)(w + (size_t)(crow + 32 * i) * D_);
            const float* g = Wg + (size_t)n0 * D_ + kc;
            #pragma unroll
            for (int gg = 0; gg < 3; ++gg)
                #pragma unroll
                for (int i = 0; i < 2; ++i)
                    pw[2 + gg * 2 + i] = *(const f32x4*)(g + (size_t)(gg * R_ + crow + 32 * i) * D_);
        } else {
            const int kc = t * BK - D_ + c4;
            const float* a = P + (size_t)m0 * MAXD + kc;
            #pragma unroll
            for (int i = 0; i < 4; ++i)
                pa[i] = *(const f32x4*)(a + (size_t)(crow + 32 * i) * MAXD);
            const float* w = Wres + (size_t)n0 * R_ + kc;
            #pragma unroll
            for (int i = 0; i < 2; ++i)
                pw[i] = *(const f32x4*)(w + (size_t)(crow + 32 * i) * R_);
        }
    };

    auto stage_A = [&]() {
        #pragma unroll
        for (int i = 0; i < 4; ++i) {
            const int r = crow + 32 * i;
            const int idx = (((r & 15) ^ q) << 3) + fbase;
            half4 h, l;
            #pragma unroll
            for (int j = 0; j < 4; ++j) {
                float v = pa[i][j];
                h[j] = (_Float16)v;
                l[j] = (_Float16)(v - (float)h[j]);
            }
            *(half4*)(&sA[0][r >> 4][idx]) = h;
            *(half4*)(&sA[1][r >> 4][idx]) = l;
        }
    };
    auto stage_W = [&](int nw) {   // nw = 8 (phase1) or 2 (phase2); literal at call site
        #pragma unroll
        for (int i = 0; i < 8; ++i) if (i < nw) {
            const int s   = (i < 2) ? 0 : 1 + ((i - 2) >> 1);
            const int sub = (i < 2) ? i : ((i - 2) & 1);
            const int r   = crow + 32 * sub;
            const int idx = (((r & 15) ^ q) << 3) + fbase;
            half4 h, l;
            #pragma unroll
            for (int j = 0; j < 4; ++j) {
                float v = pw[i][j];
                h[j] = (_Float16)v;
                l[j] = (_Float16)(v - (float)h[j]);
            }
            *(half4*)(&sW[0][s][r >> 4][idx]) = h;
            *(half4*)(&sW[1][s][r >> 4][idx]) = l;
        }
    };

#define MFMA_BLOCK(NSETS)                                                                         \
    {                                                                                             \
        half8 ah0 = *(const half8*)(&sA[0][wv * 2 + 0][raddr]);                                   \
        half8 al0 = *(const half8*)(&sA[1][wv * 2 + 0][raddr]);                                   \
        half8 ah1 = *(const half8*)(&sA[0][wv * 2 + 1][raddr]);                                   \
        half8 al1 = *(const half8*)(&sA[1][wv * 2 + 1][raddr]);                                   \
        __builtin_amdgcn_s_setprio(1);                                                            \
        _Pragma("unroll")                                                                         \
        for (int s = 0; s < NSETS; ++s) {                                                         \
            _Pragma("unroll")                                                                     \
            for (int nt = 0; nt < 4; ++nt) {                                                      \
                half8 bh = *(const half8*)(&sW[0][s][nt][raddr]);                                 \
                half8 bl = *(const half8*)(&sW[1][s][nt][raddr]);                                 \
                acc[s][0][nt] = __builtin_amdgcn_mfma_f32_16x16x32_f16(ah0, bh, acc[s][0][nt], 0, 0, 0); \
                acc[s][0][nt] = __builtin_amdgcn_mfma_f32_16x16x32_f16(al0, bh, acc[s][0][nt], 0, 0, 0); \
                acc[s][0][nt] = __builtin_amdgcn_mfma_f32_16x16x32_f16(ah0, bl, acc[s][0][nt], 0, 0, 0); \
                acc[s][1][nt] = __builtin_amdgcn_mfma_f32_16x16x32_f16(ah1, bh, acc[s][1][nt], 0, 0, 0); \
                acc[s][1][nt] = __builtin_amdgcn_mfma_f32_16x16x32_f16(al1, bh, acc[s][1][nt], 0, 0, 0); \
                acc[s][1][nt] = __builtin_amdgcn_mfma_f32_16x16x32_f16(ah1, bl, acc[s][1][nt], 0, 0, 0); \
            }                                                                                     \
        }                                                                                         \
        __builtin_amdgcn_s_setprio(0);                                                            \
    }

    issue_loads(0);

    // Phase 1: k in [0, D) -- X vs {Win, Wg i/f/o}
    #pragma unroll 1
    for (int t = 0; t < NCH1; ++t) {
        stage_A();
        stage_W(8);
        issue_loads(t + 1);      // prefetch stays in flight across both barriers
        wg_barrier();            // writes visible
        MFMA_BLOCK(4)
        wg_barrier();            // reads done before next writes
    }
    // Phase 2: k in [D, D+R) -- prev vs Wres (pre set only)
    #pragma unroll 1
    for (int t = NCH1; t < NCHUNK; ++t) {
        stage_A();
        stage_W(2);
        if (t + 1 < NCHUNK) issue_loads(t + 1);
        wg_barrier();
        MFMA_BLOCK(1)
        wg_barrier();
    }
#undef MFMA_BLOCK

    // ---- epilogue: C/D layout col=lane&15, row=quad*4+reg (m89-verified) ----
    const int fr = lane & 15;
    const int qd = lane >> 4;
    #pragma unroll
    for (int mt = 0; mt < 2; ++mt)
        #pragma unroll
        for (int nt = 0; nt < 4; ++nt)
            #pragma unroll
            for (int r = 0; r < 4; ++r) {
                int row = m0 + wv * 32 + mt * 16 + qd * 4 + r;   // batch index
                int col = n0 + nt * 16 + fr;                      // reservoir index
                float pre = acc[0][mt][nt][r];
                float ig  = sigmoidf_(acc[1][mt][nt][r]);
                float fg  = sigmoidf_(acc[2][mt][nt][r]);
                float og  = sigmoidf_(acc[3][mt][nt][r]);
                float pv  = P[(size_t)row * MAXD + col];          // exact fp32 prev
                float st  = 0.9f * (fg * pv) + 0.1f * tanhf(ig * pre);
                st *= og;
                if (st > 0.5f) st -= 0.5f;
                out[(size_t)row * MAXD + col] = st;
            }
}

// Zero the pad region out[:, 2048:2560] (harness poisons d_out with 0xAA).
__global__ void pad_zero(float* __restrict__ out) {
    int idx = blockIdx.x * 256 + threadIdx.x;
    int row = idx >> 7;
    int c   = (idx & 127) * 4;
    *(f32x4*)(&out[(size_t)row * MAXD + R_ + c]) = (f32x4){0.f, 0.f, 0.f, 0.f};
}

extern "C" void kernel_launch(void* const* d_in, const int* in_sizes, int n_in,
                              void* d_out, int out_size, void* d_ws, size_t ws_size,
                              hipStream_t stream) {
    const float* X    = (const float*)d_in[0];
    const float* P    = (const float*)d_in[1];
    const float* Win  = (const float*)d_in[2];
    const float* Wres = (const float*)d_in[3];
    const float* Wg   = (const float*)d_in[4];
    float* out        = (float*)d_out;

    pad_zero<<<2048, 256, 0, stream>>>(out);
    dim3 grid(R_ / BN, B_ / BM);   // (32, 32) = 1024 blocks
    reservoir_fused<<<grid, 256, 0, stream>>>(X, P, Win, Wres, Wg, out);
}